// Round 4
// baseline (332.955 us; speedup 1.0000x reference)
//
#include <hip/hip_runtime.h>

// LoRAConnector: B=4, T=2048, N=4, C=1024, A=8, nC=4096, SINKHORN_ITERS=20
//
// Round 5: invert decomposition to kill the LDS-bandwidth bottleneck.
//  R3 post-mortem: 384 ds_read_b128/thread (4 g-threads re-read the same phi
//  4x) = ~61us of LDS pipe per CU -> dominant term of 149us. Fix: thread t
//  owns d-element t (per tile) for ALL 4 tokens: 6 b128 reads feed 96 FMAs
//  (4x fewer LDS reads, 1B/FMA). acc grows to 24x4+4=100 regs; LDS caps
//  occupancy at 3 blocks/CU anyway -> VGPR<=170 free -> launch_bounds(256,3).
//  Reads are consecutive-lane dense -> conflict-free, NO swizzle; phi_res is
//  staged TRANSPOSED prT[q][d] via per-lane source addresses (m173 pattern,
//  LDS dest stays linear as global_load_lds requires).
//  Reduction: token-redistributing butterfly (cndmask selects, static reg
//  indices per rule #20): after bits 0,1 lane holds its token=ln&3 partials;
//  bits 2..5 finish the wave sum; cross-wave LDS path unchanged (lane e<4
//  writes token e). x/w prefetched one tile ahead to cover HBM latency.
//  Expected: LDS ~15us, VALU ~17us, HBM floor ~38us -> 55-80us/dispatch.

#define BT 8192        // B*T tokens
#define NC 4096        // N*C
#define NC4 1024       // NC/4

__global__ __launch_bounds__(256, 3) void lora_connector_kernel(
    const float* __restrict__ x,
    const float* __restrict__ inw,
    const float* __restrict__ phi_pre,
    const float* __restrict__ phi_post,
    const float* __restrict__ phi_res,
    const float* __restrict__ b_pre,
    const float* __restrict__ b_post,
    const float* __restrict__ b_res,
    const float* __restrict__ alpha_pre,
    const float* __restrict__ alpha_post,
    const float* __restrict__ alpha_res,
    const int*   __restrict__ adapter_indices,
    float* __restrict__ out)
{
    const int tid = threadIdx.x;
    const int g   = tid & 3;        // token for phase 2c/3
    const int l   = tid >> 2;       // c4-slice for phase 3
    const int wvid= tid >> 6;       // wave 0..3
    const int ln  = tid & 63;       // lane within wave
    const int blk = blockIdx.x;
    const int b   = blk >> 9;       // block-uniform batch
    const int idx = adapter_indices[b];

    const float4* __restrict__ pp4 = (const float4*)(phi_pre  + (size_t)idx * (NC * 4));
    const float4* __restrict__ po4 = (const float4*)(phi_post + (size_t)idx * (NC * 4));
    const float4* __restrict__ pr4 = (const float4*)(phi_res  + (size_t)idx * (NC * 16));
    const float*  __restrict__ inwp = inw + (size_t)idx * NC + tid;
    const float*  __restrict__ xb   = x + (size_t)(blk * 4) * NC + tid; // + j*NC + m*256

    // fused double-buffered phi tile (float4 units):
    //  [0..255]=pp[d], [256..511]=po[d], [512+q*256+d]=prT[q][d]  (transposed!)
    __shared__ float4 tileL[2][1536];
    __shared__ float red[4][4][26];

    // staging: 24 chunks of 1KB; wave wvid owns chunks c=6*wvid..6*wvid+5.
    // dest is linear (chunk c -> float4s c*64 + ln); source per-lane:
    //  c<8: linear pp/po rows;  c>=8 (k=c-8): src = pr4[d*4+q], d=(k&3)*64+ln,
    //  q=k>>2  -> lands at dest 512+64k+ln == prT[q][d]. Transpose via source.
    const float4* sg[6];
    int sstr[6];
    #pragma unroll
    for (int i = 0; i < 6; ++i) {
        const int c = wvid * 6 + i;              // wave-uniform
        const float4* bp; int off, str;
        if (c < 8) {
            bp  = (c < 4) ? pp4 : po4;
            off = ((c & 3) << 6) + ln;
            str = 256;
        } else {
            const int k = c - 8;
            bp  = pr4;
            off = ((((k & 3) << 6) + ln) << 2) + (k >> 2);
            str = 1024;
        }
        sg[i] = bp + off;
        sstr[i] = str;
    }

    #define STAGE_TILE(MT, BF)                                                   \
    {                                                                            \
        _Pragma("unroll")                                                        \
        for (int i = 0; i < 6; ++i) {                                            \
            __builtin_amdgcn_global_load_lds(                                    \
                (const __attribute__((address_space(1))) void*)(sg[i] + (size_t)(MT) * sstr[i]), \
                (__attribute__((address_space(3))) void*)&tileL[BF][(wvid * 6 + i) << 6], \
                16, 0, 0);                                                       \
        }                                                                        \
    }

    // ---- Prologue: stage tile 0; prefetch x,w for tile 0 ----
    STAGE_TILE(0, 0);

    float acc[24][4];
    float ss[4];
    #pragma unroll
    for (int j = 0; j < 24; ++j) {
        acc[j][0] = 0.0f; acc[j][1] = 0.0f; acc[j][2] = 0.0f; acc[j][3] = 0.0f;
    }
    ss[0] = ss[1] = ss[2] = ss[3] = 0.0f;

    float xn[4], wn;
    #pragma unroll
    for (int j = 0; j < 4; ++j) xn[j] = xb[j * NC];
    wn = inwp[0];

    // ---- Phase 1: 16 tiles; barrier -> stage next -> consume current ----
    #pragma unroll 1
    for (int m = 0; m < 16; ++m) {
        const int bf = m & 1;
        __syncthreads();                         // tile m resident (vmcnt drain)
        if (m < 15) STAGE_TILE(m + 1, bf ^ 1);   // phi m+1 in flight

        const float wv = wn;
        float s[4];
        #pragma unroll
        for (int j = 0; j < 4; ++j) {
            const float xv = xn[j];
            s[j] = xv * wv;
            ss[j] = fmaf(xv, xv, ss[j]);
        }
        if (m < 15) {                            // x,w m+1 in flight
            #pragma unroll
            for (int j = 0; j < 4; ++j) xn[j] = xb[j * NC + (m + 1) * 256];
            wn = inwp[(m + 1) * 256];
        }

        const float4 a = tileL[bf][tid];
        #pragma unroll
        for (int j = 0; j < 4; ++j) {
            acc[0][j] = fmaf(s[j], a.x, acc[0][j]);
            acc[1][j] = fmaf(s[j], a.y, acc[1][j]);
            acc[2][j] = fmaf(s[j], a.z, acc[2][j]);
            acc[3][j] = fmaf(s[j], a.w, acc[3][j]);
        }
        const float4 p = tileL[bf][256 + tid];
        #pragma unroll
        for (int j = 0; j < 4; ++j) {
            acc[4][j] = fmaf(s[j], p.x, acc[4][j]);
            acc[5][j] = fmaf(s[j], p.y, acc[5][j]);
            acc[6][j] = fmaf(s[j], p.z, acc[6][j]);
            acc[7][j] = fmaf(s[j], p.w, acc[7][j]);
        }
        #pragma unroll
        for (int q = 0; q < 4; ++q) {
            const float4 r = tileL[bf][512 + q * 256 + tid];
            #pragma unroll
            for (int j = 0; j < 4; ++j) {
                acc[8 + q * 4 + 0][j] = fmaf(s[j], r.x, acc[8 + q * 4 + 0][j]);
                acc[8 + q * 4 + 1][j] = fmaf(s[j], r.y, acc[8 + q * 4 + 1][j]);
                acc[8 + q * 4 + 2][j] = fmaf(s[j], r.z, acc[8 + q * 4 + 2][j]);
                acc[8 + q * 4 + 3][j] = fmaf(s[j], r.w, acc[8 + q * 4 + 3][j]);
            }
        }
    }

    // ---- Phase 2a: token-redistributing butterfly (wave sum) ----
    // bit0/bit1: combine while assigning token = ln&3 to each lane (cndmask
    // selects, all register indices static). bits 2..5: plain butterfly.
    float tot[25];
    #define RED4(V0, V1, V2, V3, DST)                                   \
    {                                                                   \
        const float u0 = (V0) + __shfl_xor((V0), 1);                    \
        const float u1 = (V1) + __shfl_xor((V1), 1);                    \
        const float u2 = (V2) + __shfl_xor((V2), 1);                    \
        const float u3 = (V3) + __shfl_xor((V3), 1);                    \
        const float r0 = (ln & 1) ? u1 : u0;                            \
        const float r1 = (ln & 1) ? u3 : u2;                            \
        const float w0 = r0 + __shfl_xor(r0, 2);                        \
        const float w1 = r1 + __shfl_xor(r1, 2);                        \
        float tv = (ln & 2) ? w1 : w0;                                  \
        tv += __shfl_xor(tv, 4);  tv += __shfl_xor(tv, 8);              \
        tv += __shfl_xor(tv, 16); tv += __shfl_xor(tv, 32);             \
        (DST) = tv;                                                     \
    }
    #pragma unroll
    for (int j = 0; j < 24; ++j)
        RED4(acc[j][0], acc[j][1], acc[j][2], acc[j][3], tot[j]);
    RED4(ss[0], ss[1], ss[2], ss[3], tot[24]);
    #undef RED4

    // ---- Phase 2b: cross-wave reduction via LDS (lane e<4 holds token e) ----
    if (ln < 4) {
        #pragma unroll
        for (int j = 0; j < 25; ++j) red[wvid][ln][j] = tot[j];
    }
    __syncthreads();
    #pragma unroll
    for (int j = 0; j < 25; ++j)
        tot[j] = (red[0][g][j] + red[1][g][j]) + (red[2][g][j] + red[3][g][j]);

    // ---- Phase 2c: rms, gates, sinkhorn (token g per thread) ----
    const float inv_rms = rsqrtf(tot[24] * (1.0f / 4096.0f) + 1e-5f);
    const float apre  = alpha_pre[idx];
    const float apost = alpha_post[idx];
    const float ares  = alpha_res[idx];

    float Hpre[4], Hpost[4];
    #pragma unroll
    for (int n = 0; n < 4; ++n) {
        const float zp = fmaf(apre,  tot[n]     * inv_rms, b_pre[idx * 4 + n]);
        Hpre[n]  = 1.0f / (1.0f + __expf(-zp));
        const float zq = fmaf(apost, tot[4 + n] * inv_rms, b_post[idx * 4 + n]);
        Hpost[n] = 2.0f / (1.0f + __expf(-zq));
    }

    // lane owns element (si,sj) of token g's 4x4 matrix
    const int s16 = ln >> 2;         // 0..15
    const int sj = s16 & 3;
    const int si = s16 >> 2;
    float Mv = __expf(fmaf(ares, tot[8 + si * 4 + sj] * inv_rms,
                           b_res[idx * 16 + si * 4 + sj]));
    #pragma unroll
    for (int it = 0; it < 20; ++it) {
        float rs = Mv + __shfl_xor(Mv, 4);   // sum over j (lane bits 2,3)
        rs += __shfl_xor(rs, 8);
        Mv *= __builtin_amdgcn_rcpf(rs);
        float cs = Mv + __shfl_xor(Mv, 16);  // sum over i (lane bits 4,5)
        cs += __shfl_xor(cs, 32);
        Mv *= __builtin_amdgcn_rcpf(cs);
    }

    // gather full W[i][j] = M[i][j] + Hpost[i]*Hpre[j] for this thread's token
    float W[4][4];
    #pragma unroll
    for (int sq = 0; sq < 16; ++sq) {
        const float mm = __shfl(Mv, sq * 4 + g);
        W[sq >> 2][sq & 3] = fmaf(Hpost[sq >> 2], Hpre[sq & 3], mm);
    }

    // ---- Phase 3: out[tok][i*256+c4] = sum_j W[i][j] * x[tok][j*256+c4] ----
    const int tok = blk * 4 + g;
    const float4* __restrict__ x4p = (const float4*)x + (size_t)tok * NC4;
    float4* __restrict__ out4 = (float4*)out + (size_t)tok * NC4;
    #pragma unroll
    for (int k = 0; k < 4; ++k) {
        const int c4 = k * 64 + l;
        const float4 x0 = x4p[0 * 256 + c4];
        const float4 x1 = x4p[1 * 256 + c4];
        const float4 x2 = x4p[2 * 256 + c4];
        const float4 x3 = x4p[3 * 256 + c4];
        #pragma unroll
        for (int i = 0; i < 4; ++i) {
            float4 o;
            o.x = fmaf(W[i][0], x0.x, fmaf(W[i][1], x1.x, fmaf(W[i][2], x2.x, W[i][3] * x3.x)));
            o.y = fmaf(W[i][0], x0.y, fmaf(W[i][1], x1.y, fmaf(W[i][2], x2.y, W[i][3] * x3.y)));
            o.z = fmaf(W[i][0], x0.z, fmaf(W[i][1], x1.z, fmaf(W[i][2], x2.z, W[i][3] * x3.z)));
            o.w = fmaf(W[i][0], x0.w, fmaf(W[i][1], x1.w, fmaf(W[i][2], x2.w, W[i][3] * x3.w)));
            out4[i * 256 + c4] = o;
        }
    }
    #undef STAGE_TILE
}

extern "C" void kernel_launch(void* const* d_in, const int* in_sizes, int n_in,
                              void* d_out, int out_size, void* d_ws, size_t ws_size,
                              hipStream_t stream) {
    const float* x         = (const float*)d_in[0];
    const float* inw       = (const float*)d_in[1];
    const float* phi_pre   = (const float*)d_in[2];
    const float* phi_post  = (const float*)d_in[3];
    const float* phi_res   = (const float*)d_in[4];
    const float* b_pre     = (const float*)d_in[5];
    const float* b_post    = (const float*)d_in[6];
    const float* b_res     = (const float*)d_in[7];
    const float* alpha_pre = (const float*)d_in[8];
    const float* alpha_post= (const float*)d_in[9];
    const float* alpha_res = (const float*)d_in[10];
    const int*   adapter   = (const int*)d_in[11];
    float* out = (float*)d_out;

    dim3 grid(BT / 4);   // 2048 blocks, 4 tokens each
    dim3 block(256);
    lora_connector_kernel<<<grid, block, 0, stream>>>(
        x, inw, phi_pre, phi_post, phi_res,
        b_pre, b_post, b_res,
        alpha_pre, alpha_post, alpha_res,
        adapter, out);
}

// Round 5
// 332.622 us; speedup vs baseline: 1.0010x; 1.0010x over previous
//
#include <hip/hip_runtime.h>

// LoRAConnector: B=4, T=2048, N=4, C=1024, A=8, nC=4096, SINKHORN_ITERS=20
//
// Round 6: R4 structure + pinned waves-per-EU to kill the spill.
//  R4 post-mortem: VGPR=80 < 100 live accs -> ~33 floats/thread scratch
//  (WRITE_SIZE +66MB, FETCH +22MB). launch_bounds(256,3) only sets a reg CAP
//  (min-occupancy guarantee); the allocator's own heuristic targeted 6
//  waves/EU (80 regs) because it ignores the LDS limit (51.2KB -> 3 blocks/CU
//  = 3 waves/EU regardless). Fix: amdgpu_waves_per_eu(3,3) pins min=max=3 ->
//  budget 512/3~=168 regs and no incentive to shrink; live set ~140 fits.
//  Everything else byte-identical to R4 (clean A/B):
//   - thread owns d-element tid (per 256-d tile) for ALL 4 tokens: 6
//     ds_read_b128 feed 96 FMAs (minimum possible LDS traffic, ~15us/CU).
//   - phi staged via global_load_lds double-buffer; linear LDS dest; phi_res
//     transposed via per-lane SOURCE addresses (m173); dense consecutive-lane
//     reads -> conflict-free, no swizzle (R4: SQ_LDS_BANK_CONFLICT=0).
//   - token-redistributing butterfly reduction (static reg indices, rule #20).
//  Validation gates: VGPR 136-168, WRITE_SIZE == 131072 KB exactly.
//  If VGPR still <=100: attribute ignored -> fall back to 2-token split.

#define BT 8192        // B*T tokens
#define NC 4096        // N*C
#define NC4 1024       // NC/4

__global__ __attribute__((amdgpu_waves_per_eu(3, 3))) __launch_bounds__(256)
void lora_connector_kernel(
    const float* __restrict__ x,
    const float* __restrict__ inw,
    const float* __restrict__ phi_pre,
    const float* __restrict__ phi_post,
    const float* __restrict__ phi_res,
    const float* __restrict__ b_pre,
    const float* __restrict__ b_post,
    const float* __restrict__ b_res,
    const float* __restrict__ alpha_pre,
    const float* __restrict__ alpha_post,
    const float* __restrict__ alpha_res,
    const int*   __restrict__ adapter_indices,
    float* __restrict__ out)
{
    const int tid = threadIdx.x;
    const int g   = tid & 3;        // token for phase 2c/3
    const int l   = tid >> 2;       // c4-slice for phase 3
    const int wvid= tid >> 6;       // wave 0..3
    const int ln  = tid & 63;       // lane within wave
    const int blk = blockIdx.x;
    const int b   = blk >> 9;       // block-uniform batch
    const int idx = adapter_indices[b];

    const float4* __restrict__ pp4 = (const float4*)(phi_pre  + (size_t)idx * (NC * 4));
    const float4* __restrict__ po4 = (const float4*)(phi_post + (size_t)idx * (NC * 4));
    const float4* __restrict__ pr4 = (const float4*)(phi_res  + (size_t)idx * (NC * 16));
    const float*  __restrict__ inwp = inw + (size_t)idx * NC + tid;
    const float*  __restrict__ xb   = x + (size_t)(blk * 4) * NC + tid; // + j*NC + m*256

    // fused double-buffered phi tile (float4 units):
    //  [0..255]=pp[d], [256..511]=po[d], [512+q*256+d]=prT[q][d]  (transposed!)
    __shared__ float4 tileL[2][1536];
    __shared__ float red[4][4][26];

    // staging: 24 chunks of 1KB; wave wvid owns chunks c=6*wvid..6*wvid+5.
    // dest is linear (chunk c -> float4s c*64 + ln); source per-lane:
    //  c<8: linear pp/po rows;  c>=8 (k=c-8): src = pr4[d*4+q], d=(k&3)*64+ln,
    //  q=k>>2  -> lands at dest 512+64k+ln == prT[q][d]. Transpose via source.
    const float4* sg[6];
    int sstr[6];
    #pragma unroll
    for (int i = 0; i < 6; ++i) {
        const int c = wvid * 6 + i;              // wave-uniform
        const float4* bp; int off, str;
        if (c < 8) {
            bp  = (c < 4) ? pp4 : po4;
            off = ((c & 3) << 6) + ln;
            str = 256;
        } else {
            const int k = c - 8;
            bp  = pr4;
            off = ((((k & 3) << 6) + ln) << 2) + (k >> 2);
            str = 1024;
        }
        sg[i] = bp + off;
        sstr[i] = str;
    }

    #define STAGE_TILE(MT, BF)                                                   \
    {                                                                            \
        _Pragma("unroll")                                                        \
        for (int i = 0; i < 6; ++i) {                                            \
            __builtin_amdgcn_global_load_lds(                                    \
                (const __attribute__((address_space(1))) void*)(sg[i] + (size_t)(MT) * sstr[i]), \
                (__attribute__((address_space(3))) void*)&tileL[BF][(wvid * 6 + i) << 6], \
                16, 0, 0);                                                       \
        }                                                                        \
    }

    // ---- Prologue: stage tile 0; prefetch x,w for tile 0 ----
    STAGE_TILE(0, 0);

    float acc[24][4];
    float ss[4];
    #pragma unroll
    for (int j = 0; j < 24; ++j) {
        acc[j][0] = 0.0f; acc[j][1] = 0.0f; acc[j][2] = 0.0f; acc[j][3] = 0.0f;
    }
    ss[0] = ss[1] = ss[2] = ss[3] = 0.0f;

    float xn[4], wn;
    #pragma unroll
    for (int j = 0; j < 4; ++j) xn[j] = xb[j * NC];
    wn = inwp[0];

    // ---- Phase 1: 16 tiles; barrier -> stage next -> consume current ----
    #pragma unroll 1
    for (int m = 0; m < 16; ++m) {
        const int bf = m & 1;
        __syncthreads();                         // tile m resident (vmcnt drain)
        if (m < 15) STAGE_TILE(m + 1, bf ^ 1);   // phi m+1 in flight

        const float wv = wn;
        float s[4];
        #pragma unroll
        for (int j = 0; j < 4; ++j) {
            const float xv = xn[j];
            s[j] = xv * wv;
            ss[j] = fmaf(xv, xv, ss[j]);
        }
        if (m < 15) {                            // x,w m+1 in flight
            #pragma unroll
            for (int j = 0; j < 4; ++j) xn[j] = xb[j * NC + (m + 1) * 256];
            wn = inwp[(m + 1) * 256];
        }

        const float4 a = tileL[bf][tid];
        #pragma unroll
        for (int j = 0; j < 4; ++j) {
            acc[0][j] = fmaf(s[j], a.x, acc[0][j]);
            acc[1][j] = fmaf(s[j], a.y, acc[1][j]);
            acc[2][j] = fmaf(s[j], a.z, acc[2][j]);
            acc[3][j] = fmaf(s[j], a.w, acc[3][j]);
        }
        const float4 p = tileL[bf][256 + tid];
        #pragma unroll
        for (int j = 0; j < 4; ++j) {
            acc[4][j] = fmaf(s[j], p.x, acc[4][j]);
            acc[5][j] = fmaf(s[j], p.y, acc[5][j]);
            acc[6][j] = fmaf(s[j], p.z, acc[6][j]);
            acc[7][j] = fmaf(s[j], p.w, acc[7][j]);
        }
        #pragma unroll
        for (int q = 0; q < 4; ++q) {
            const float4 r = tileL[bf][512 + q * 256 + tid];
            #pragma unroll
            for (int j = 0; j < 4; ++j) {
                acc[8 + q * 4 + 0][j] = fmaf(s[j], r.x, acc[8 + q * 4 + 0][j]);
                acc[8 + q * 4 + 1][j] = fmaf(s[j], r.y, acc[8 + q * 4 + 1][j]);
                acc[8 + q * 4 + 2][j] = fmaf(s[j], r.z, acc[8 + q * 4 + 2][j]);
                acc[8 + q * 4 + 3][j] = fmaf(s[j], r.w, acc[8 + q * 4 + 3][j]);
            }
        }
    }

    // ---- Phase 2a: token-redistributing butterfly (wave sum) ----
    // bit0/bit1: combine while assigning token = ln&3 to each lane (cndmask
    // selects, all register indices static). bits 2..5: plain butterfly.
    float tot[25];
    #define RED4(V0, V1, V2, V3, DST)                                   \
    {                                                                   \
        const float u0 = (V0) + __shfl_xor((V0), 1);                    \
        const float u1 = (V1) + __shfl_xor((V1), 1);                    \
        const float u2 = (V2) + __shfl_xor((V2), 1);                    \
        const float u3 = (V3) + __shfl_xor((V3), 1);                    \
        const float r0 = (ln & 1) ? u1 : u0;                            \
        const float r1 = (ln & 1) ? u3 : u2;                            \
        const float w0 = r0 + __shfl_xor(r0, 2);                        \
        const float w1 = r1 + __shfl_xor(r1, 2);                        \
        float tv = (ln & 2) ? w1 : w0;                                  \
        tv += __shfl_xor(tv, 4);  tv += __shfl_xor(tv, 8);              \
        tv += __shfl_xor(tv, 16); tv += __shfl_xor(tv, 32);             \
        (DST) = tv;                                                     \
    }
    #pragma unroll
    for (int j = 0; j < 24; ++j)
        RED4(acc[j][0], acc[j][1], acc[j][2], acc[j][3], tot[j]);
    RED4(ss[0], ss[1], ss[2], ss[3], tot[24]);
    #undef RED4

    // ---- Phase 2b: cross-wave reduction via LDS (lane e<4 holds token e) ----
    if (ln < 4) {
        #pragma unroll
        for (int j = 0; j < 25; ++j) red[wvid][ln][j] = tot[j];
    }
    __syncthreads();
    #pragma unroll
    for (int j = 0; j < 25; ++j)
        tot[j] = (red[0][g][j] + red[1][g][j]) + (red[2][g][j] + red[3][g][j]);

    // ---- Phase 2c: rms, gates, sinkhorn (token g per thread) ----
    const float inv_rms = rsqrtf(tot[24] * (1.0f / 4096.0f) + 1e-5f);
    const float apre  = alpha_pre[idx];
    const float apost = alpha_post[idx];
    const float ares  = alpha_res[idx];

    float Hpre[4], Hpost[4];
    #pragma unroll
    for (int n = 0; n < 4; ++n) {
        const float zp = fmaf(apre,  tot[n]     * inv_rms, b_pre[idx * 4 + n]);
        Hpre[n]  = 1.0f / (1.0f + __expf(-zp));
        const float zq = fmaf(apost, tot[4 + n] * inv_rms, b_post[idx * 4 + n]);
        Hpost[n] = 2.0f / (1.0f + __expf(-zq));
    }

    // lane owns element (si,sj) of token g's 4x4 matrix
    const int s16 = ln >> 2;         // 0..15
    const int sj = s16 & 3;
    const int si = s16 >> 2;
    float Mv = __expf(fmaf(ares, tot[8 + si * 4 + sj] * inv_rms,
                           b_res[idx * 16 + si * 4 + sj]));
    #pragma unroll
    for (int it = 0; it < 20; ++it) {
        float rs = Mv + __shfl_xor(Mv, 4);   // sum over j (lane bits 2,3)
        rs += __shfl_xor(rs, 8);
        Mv *= __builtin_amdgcn_rcpf(rs);
        float cs = Mv + __shfl_xor(Mv, 16);  // sum over i (lane bits 4,5)
        cs += __shfl_xor(cs, 32);
        Mv *= __builtin_amdgcn_rcpf(cs);
    }

    // gather full W[i][j] = M[i][j] + Hpost[i]*Hpre[j] for this thread's token
    float W[4][4];
    #pragma unroll
    for (int sq = 0; sq < 16; ++sq) {
        const float mm = __shfl(Mv, sq * 4 + g);
        W[sq >> 2][sq & 3] = fmaf(Hpost[sq >> 2], Hpre[sq & 3], mm);
    }

    // ---- Phase 3: out[tok][i*256+c4] = sum_j W[i][j] * x[tok][j*256+c4] ----
    const int tok = blk * 4 + g;
    const float4* __restrict__ x4p = (const float4*)x + (size_t)tok * NC4;
    float4* __restrict__ out4 = (float4*)out + (size_t)tok * NC4;
    #pragma unroll
    for (int k = 0; k < 4; ++k) {
        const int c4 = k * 64 + l;
        const float4 x0 = x4p[0 * 256 + c4];
        const float4 x1 = x4p[1 * 256 + c4];
        const float4 x2 = x4p[2 * 256 + c4];
        const float4 x3 = x4p[3 * 256 + c4];
        #pragma unroll
        for (int i = 0; i < 4; ++i) {
            float4 o;
            o.x = fmaf(W[i][0], x0.x, fmaf(W[i][1], x1.x, fmaf(W[i][2], x2.x, W[i][3] * x3.x)));
            o.y = fmaf(W[i][0], x0.y, fmaf(W[i][1], x1.y, fmaf(W[i][2], x2.y, W[i][3] * x3.y)));
            o.z = fmaf(W[i][0], x0.z, fmaf(W[i][1], x1.z, fmaf(W[i][2], x2.z, W[i][3] * x3.z)));
            o.w = fmaf(W[i][0], x0.w, fmaf(W[i][1], x1.w, fmaf(W[i][2], x2.w, W[i][3] * x3.w)));
            out4[i * 256 + c4] = o;
        }
    }
    #undef STAGE_TILE
}

extern "C" void kernel_launch(void* const* d_in, const int* in_sizes, int n_in,
                              void* d_out, int out_size, void* d_ws, size_t ws_size,
                              hipStream_t stream) {
    const float* x         = (const float*)d_in[0];
    const float* inw       = (const float*)d_in[1];
    const float* phi_pre   = (const float*)d_in[2];
    const float* phi_post  = (const float*)d_in[3];
    const float* phi_res   = (const float*)d_in[4];
    const float* b_pre     = (const float*)d_in[5];
    const float* b_post    = (const float*)d_in[6];
    const float* b_res     = (const float*)d_in[7];
    const float* alpha_pre = (const float*)d_in[8];
    const float* alpha_post= (const float*)d_in[9];
    const float* alpha_res = (const float*)d_in[10];
    const int*   adapter   = (const int*)d_in[11];
    float* out = (float*)d_out;

    dim3 grid(BT / 4);   // 2048 blocks, 4 tokens each
    dim3 block(256);
    lora_connector_kernel<<<grid, block, 0, stream>>>(
        x, inw, phi_pre, phi_post, phi_res,
        b_pre, b_post, b_res,
        alpha_pre, alpha_post, alpha_res,
        adapter, out);
}

// Round 6
// 309.839 us; speedup vs baseline: 1.0746x; 1.0735x over previous
//
#include <hip/hip_runtime.h>

// LoRAConnector: B=4, T=2048, N=4, C=1024, A=8, nC=4096, SINKHORN_ITERS=20
//
// Round 7: occupancy x2 + no-spill via (half-split outputs, BK=128 tiles).
//  R5 post-mortem: waves_per_eu(3,3) ignored (VGPR still 80, spill still
//  ~66MB, dur identical) -> can't raise the reg budget; must fit UNDER 80.
//  Also R4 vs R3 proved LDS reads weren't the critical path; both are
//  latency-bound at 12 waves/CU (LDS 51.2KB -> 3 blocks).
//  Changes vs R5 (work assignment only; math identical):
//   - tile BK=128 d's (12KB): dbuf 24KB + red 0.9KB = 25.5KB -> 6 blocks/CU
//     = 24 waves/CU (2x latency hiding). 32 tiles.
//   - 256 threads = (d_local 0..127) x (half 0..1). half is wave-uniform
//     (waves 0,1 = half0; waves 2,3 = half1). Thread keeps 4 tokens but only
//     12 of 24 outputs: half0 = pp(4)+po(4)+res[0..3]; half1 = res[4..15].
//     acc[12][4]+ss[4] = 52 live -> ~78 total < 80-reg clamp -> no spill.
//     Token-sharing preserved -> LDS reads stay at R4 minimum (3 b128/thread
//     /tile; 2-way same-addr across halves is broadcast, free).
//   - LDS layout [0..127]=pp[d],[128..255]=po[d],[256+q*128+d]=prT[q][d];
//     12 chunks of 1KB/tile, 3 per wave; dest = tileL[bf][c*64+ln] (linear,
//     as global_load_lds requires); phi_res transposed via per-lane SOURCE
//     address (m173). Reads consecutive-lane dense -> conflict-free.
//  Gates: WRITE_SIZE == 131072 KB exactly; VGPR 72-84; Occupancy 50-70%.

#define BT 8192        // B*T tokens
#define NC 4096        // N*C
#define NC4 1024       // NC/4
#define NT 32          // tiles
#define TD 128         // d's per tile

__global__ __launch_bounds__(256) void lora_connector_kernel(
    const float* __restrict__ x,
    const float* __restrict__ inw,
    const float* __restrict__ phi_pre,
    const float* __restrict__ phi_post,
    const float* __restrict__ phi_res,
    const float* __restrict__ b_pre,
    const float* __restrict__ b_post,
    const float* __restrict__ b_res,
    const float* __restrict__ alpha_pre,
    const float* __restrict__ alpha_post,
    const float* __restrict__ alpha_res,
    const int*   __restrict__ adapter_indices,
    float* __restrict__ out)
{
    const int tid = threadIdx.x;
    const int g   = tid & 3;        // token for phase 2c/3
    const int l   = tid >> 2;       // c4-slice for phase 3
    const int wvid= tid >> 6;       // wave 0..3
    const int ln  = tid & 63;       // lane within wave
    const int dl  = tid & 127;      // d-slice within tile
    const int half= tid >> 7;       // output half (wave-uniform)
    const int blk = blockIdx.x;
    const int b   = blk >> 9;       // block-uniform batch
    const int idx = adapter_indices[b];

    const float4* __restrict__ pp4 = (const float4*)(phi_pre  + (size_t)idx * (NC * 4));
    const float4* __restrict__ po4 = (const float4*)(phi_post + (size_t)idx * (NC * 4));
    const float4* __restrict__ pr4 = (const float4*)(phi_res  + (size_t)idx * (NC * 16));
    const float*  __restrict__ inwp = inw + (size_t)idx * NC + dl;      // + m*TD
    const float*  __restrict__ xb   = x + (size_t)(blk * 4) * NC + dl;  // + j*NC + m*TD

    // double-buffered phi tile, 768 float4 = 12KB per buffer:
    //  [0..127]=pp[d], [128..255]=po[d], [256+q*128+d]=prT[q][d]
    __shared__ float4 tileL[2][768];
    __shared__ float red[4][4][14];

    // staging: 12 chunks of 1KB per tile; wave wvid owns chunks 3*wvid..+2.
    // dest = tileL[bf][c*64+ln] (linear). source per-lane:
    //  c<2: pp d=(c&1)*64+ln; c<4: po;  c>=4: k=c-4, q=k>>1, subd=(k&1)*64+ln,
    //  src = pr4[subd*4+q] (+ m*512 per tile) -> lands at prT[q][subd].
    const float4* sg[3];
    int sstr[3];
    #pragma unroll
    for (int i = 0; i < 3; ++i) {
        const int c = wvid * 3 + i;              // wave-uniform
        const float4* bp; int off, str;
        if (c < 4) {
            bp  = (c < 2) ? pp4 : po4;
            off = ((c & 1) << 6) + ln;
            str = TD;                            // 128 float4 per tile
        } else {
            const int k = c - 4;
            bp  = pr4;
            off = ((((k & 1) << 6) + ln) << 2) + (k >> 1);
            str = TD * 4;                        // 512 float4 per tile
        }
        sg[i] = bp + off;
        sstr[i] = str;
    }

    #define STAGE_TILE(MT, BF)                                                   \
    {                                                                            \
        _Pragma("unroll")                                                        \
        for (int i = 0; i < 3; ++i) {                                            \
            __builtin_amdgcn_global_load_lds(                                    \
                (const __attribute__((address_space(1))) void*)(sg[i] + (size_t)(MT) * sstr[i]), \
                (__attribute__((address_space(3))) void*)&tileL[BF][((wvid * 3 + i) << 6) + ln], \
                16, 0, 0);                                                       \
        }                                                                        \
    }

    // ---- Prologue: stage tile 0; prefetch x,w for tile 0 ----
    STAGE_TILE(0, 0);

    float acc[12][4];
    float ss[4];
    #pragma unroll
    for (int j = 0; j < 12; ++j) {
        acc[j][0] = 0.0f; acc[j][1] = 0.0f; acc[j][2] = 0.0f; acc[j][3] = 0.0f;
    }
    ss[0] = ss[1] = ss[2] = ss[3] = 0.0f;

    float xn[4], wn;
    #pragma unroll
    for (int j = 0; j < 4; ++j) xn[j] = xb[j * NC];
    wn = inwp[0];

    const int ba = half * 384 + dl;  // this thread's 3 reads: ba, ba+128, ba+256

    // ---- Phase 1: 32 tiles; barrier -> stage next -> consume current ----
    #pragma unroll 1
    for (int m = 0; m < NT; ++m) {
        const int bf = m & 1;
        __syncthreads();                         // tile m resident (vmcnt drain)
        if (m < NT - 1) STAGE_TILE(m + 1, bf ^ 1);   // phi m+1 in flight

        const float wv = wn;
        float s[4];
        #pragma unroll
        for (int j = 0; j < 4; ++j) {
            const float xv = xn[j];
            s[j] = xv * wv;
            ss[j] = fmaf(xv, xv, ss[j]);         // duplicated across halves; only half0's used
        }
        if (m < NT - 1) {                        // x,w m+1 in flight
            #pragma unroll
            for (int j = 0; j < 4; ++j) xn[j] = xb[j * NC + (m + 1) * TD];
            wn = inwp[(m + 1) * TD];
        }

        const float4 a = tileL[bf][ba];          // half0: pp[d]   half1: prT[1][d]
        const float4 p = tileL[bf][ba + 128];    // half0: po[d]   half1: prT[2][d]
        const float4 r = tileL[bf][ba + 256];    // half0: prT[0]  half1: prT[3][d]
        #pragma unroll
        for (int j = 0; j < 4; ++j) {
            acc[0][j]  = fmaf(s[j], a.x, acc[0][j]);
            acc[1][j]  = fmaf(s[j], a.y, acc[1][j]);
            acc[2][j]  = fmaf(s[j], a.z, acc[2][j]);
            acc[3][j]  = fmaf(s[j], a.w, acc[3][j]);
            acc[4][j]  = fmaf(s[j], p.x, acc[4][j]);
            acc[5][j]  = fmaf(s[j], p.y, acc[5][j]);
            acc[6][j]  = fmaf(s[j], p.z, acc[6][j]);
            acc[7][j]  = fmaf(s[j], p.w, acc[7][j]);
            acc[8][j]  = fmaf(s[j], r.x, acc[8][j]);
            acc[9][j]  = fmaf(s[j], r.y, acc[9][j]);
            acc[10][j] = fmaf(s[j], r.z, acc[10][j]);
            acc[11][j] = fmaf(s[j], r.w, acc[11][j]);
        }
    }

    // ---- Phase 2a: token-redistributing butterfly (wave sum) ----
    // bits 0,1 combine while assigning token = ln&3 (static reg indices,
    // rule #20); bits 2..5 finish. Lane ends holding token (ln&3)'s sums.
    float t12[13];
    #define RED4(V0, V1, V2, V3, DST)                                   \
    {                                                                   \
        const float u0 = (V0) + __shfl_xor((V0), 1);                    \
        const float u1 = (V1) + __shfl_xor((V1), 1);                    \
        const float u2 = (V2) + __shfl_xor((V2), 1);                    \
        const float u3 = (V3) + __shfl_xor((V3), 1);                    \
        const float r0 = (ln & 1) ? u1 : u0;                            \
        const float r1 = (ln & 1) ? u3 : u2;                            \
        const float w0 = r0 + __shfl_xor(r0, 2);                        \
        const float w1 = r1 + __shfl_xor(r1, 2);                        \
        float tv = (ln & 2) ? w1 : w0;                                  \
        tv += __shfl_xor(tv, 4);  tv += __shfl_xor(tv, 8);              \
        tv += __shfl_xor(tv, 16); tv += __shfl_xor(tv, 32);             \
        (DST) = tv;                                                     \
    }
    #pragma unroll
    for (int j = 0; j < 12; ++j)
        RED4(acc[j][0], acc[j][1], acc[j][2], acc[j][3], t12[j]);
    RED4(ss[0], ss[1], ss[2], ss[3], t12[12]);
    #undef RED4

    // ---- Phase 2b: cross-wave/-half assembly via LDS ----
    // waves 0,1 (half0): outputs are tot[0..11] + ss; waves 2,3: tot[12..23].
    if (ln < 4) {
        #pragma unroll
        for (int j = 0; j < 13; ++j) red[wvid][ln][j] = t12[j];
    }
    __syncthreads();
    float tot[25];
    #pragma unroll
    for (int j = 0; j < 12; ++j) {
        tot[j]      = red[0][g][j] + red[1][g][j];
        tot[12 + j] = red[2][g][j] + red[3][g][j];
    }
    tot[24] = red[0][g][12] + red[1][g][12];

    // ---- Phase 2c: rms, gates, sinkhorn (token g per thread) ----
    const float inv_rms = rsqrtf(tot[24] * (1.0f / 4096.0f) + 1e-5f);
    const float apre  = alpha_pre[idx];
    const float apost = alpha_post[idx];
    const float ares  = alpha_res[idx];

    float Hpre[4], Hpost[4];
    #pragma unroll
    for (int n = 0; n < 4; ++n) {
        const float zp = fmaf(apre,  tot[n]     * inv_rms, b_pre[idx * 4 + n]);
        Hpre[n]  = 1.0f / (1.0f + __expf(-zp));
        const float zq = fmaf(apost, tot[4 + n] * inv_rms, b_post[idx * 4 + n]);
        Hpost[n] = 2.0f / (1.0f + __expf(-zq));
    }

    // lane owns element (si,sj) of token g's 4x4 matrix
    const int s16 = ln >> 2;         // 0..15
    const int sj = s16 & 3;
    const int si = s16 >> 2;
    float Mv = __expf(fmaf(ares, tot[8 + si * 4 + sj] * inv_rms,
                           b_res[idx * 16 + si * 4 + sj]));
    #pragma unroll
    for (int it = 0; it < 20; ++it) {
        float rs = Mv + __shfl_xor(Mv, 4);   // sum over j (lane bits 2,3)
        rs += __shfl_xor(rs, 8);
        Mv *= __builtin_amdgcn_rcpf(rs);
        float cs = Mv + __shfl_xor(Mv, 16);  // sum over i (lane bits 4,5)
        cs += __shfl_xor(cs, 32);
        Mv *= __builtin_amdgcn_rcpf(cs);
    }

    // gather full W[i][j] = M[i][j] + Hpost[i]*Hpre[j] for this thread's token
    float W[4][4];
    #pragma unroll
    for (int sq = 0; sq < 16; ++sq) {
        const float mm = __shfl(Mv, sq * 4 + g);
        W[sq >> 2][sq & 3] = fmaf(Hpost[sq >> 2], Hpre[sq & 3], mm);
    }

    // ---- Phase 3: out[tok][i*256+c4] = sum_j W[i][j] * x[tok][j*256+c4] ----
    const int tok = blk * 4 + g;
    const float4* __restrict__ x4p = (const float4*)x + (size_t)tok * NC4;
    float4* __restrict__ out4 = (float4*)out + (size_t)tok * NC4;
    #pragma unroll
    for (int k = 0; k < 4; ++k) {
        const int c4 = k * 64 + l;
        const float4 x0 = x4p[0 * 256 + c4];
        const float4 x1 = x4p[1 * 256 + c4];
        const float4 x2 = x4p[2 * 256 + c4];
        const float4 x3 = x4p[3 * 256 + c4];
        #pragma unroll
        for (int i = 0; i < 4; ++i) {
            float4 o;
            o.x = fmaf(W[i][0], x0.x, fmaf(W[i][1], x1.x, fmaf(W[i][2], x2.x, W[i][3] * x3.x)));
            o.y = fmaf(W[i][0], x0.y, fmaf(W[i][1], x1.y, fmaf(W[i][2], x2.y, W[i][3] * x3.y)));
            o.z = fmaf(W[i][0], x0.z, fmaf(W[i][1], x1.z, fmaf(W[i][2], x2.z, W[i][3] * x3.z)));
            o.w = fmaf(W[i][0], x0.w, fmaf(W[i][1], x1.w, fmaf(W[i][2], x2.w, W[i][3] * x3.w)));
            out4[i * 256 + c4] = o;
        }
    }
    #undef STAGE_TILE
}

extern "C" void kernel_launch(void* const* d_in, const int* in_sizes, int n_in,
                              void* d_out, int out_size, void* d_ws, size_t ws_size,
                              hipStream_t stream) {
    const float* x         = (const float*)d_in[0];
    const float* inw       = (const float*)d_in[1];
    const float* phi_pre   = (const float*)d_in[2];
    const float* phi_post  = (const float*)d_in[3];
    const float* phi_res   = (const float*)d_in[4];
    const float* b_pre     = (const float*)d_in[5];
    const float* b_post    = (const float*)d_in[6];
    const float* b_res     = (const float*)d_in[7];
    const float* alpha_pre = (const float*)d_in[8];
    const float* alpha_post= (const float*)d_in[9];
    const float* alpha_res = (const float*)d_in[10];
    const int*   adapter   = (const int*)d_in[11];
    float* out = (float*)d_out;

    dim3 grid(BT / 4);   // 2048 blocks, 4 tokens each
    dim3 block(256);
    lora_connector_kernel<<<grid, block, 0, stream>>>(
        x, inw, phi_pre, phi_post, phi_res,
        b_pre, b_post, b_res,
        alpha_pre, alpha_post, alpha_res,
        adapter, out);
}